// Round 4
// baseline (231.098 us; speedup 1.0000x reference)
//
#include <hip/hip_runtime.h>
#include <stdint.h>

#define NB    4096u          // partition buckets
#define BMASK (NB - 1u)
#define CAPB  1536u          // record capacity per bucket (mean 1024, +16 sigma)
#define LCAP  2048u          // LDS hash-table capacity (per table)
#define LMASK (LCAP - 1u)
#define EMPTY 0xFFFFFFFFu
#define MAXIT (CAPB / 256u)  // 6 records per thread max in count kernel

__device__ __forceinline__ uint32_t hash32(uint32_t x) {
    x *= 2654435761u;
    x ^= x >> 16;
    x *= 0x85ebca6bu;
    x ^= x >> 13;
    return x;
}

// ckey = 30-bit context key (t3,t2,t1), t0 = current token
__device__ __forceinline__ void make_keys(const int* __restrict__ tok, int i,
                                          uint32_t& ckey, uint32_t& t0) {
    t0 = (uint32_t)tok[i];
    uint32_t t1 = (i >= 1) ? (uint32_t)tok[i - 1] : 0u;
    uint32_t t2 = (i >= 2) ? (uint32_t)tok[i - 2] : 0u;
    uint32_t t3 = (i >= 3) ? (uint32_t)tok[i - 3] : 0u;
    ckey = (t3 << 20) | (t2 << 10) | t1;
}

// Partition positions into NB buckets by hash(ckey) bits 20..31.
// Record: u64 = (pkey40 << 22) | pos22 ; weight carried in parallel wrec[].
__global__ void scatter_kernel(const int* __restrict__ tok,
                               const float* __restrict__ w,
                               unsigned long long* __restrict__ rec,
                               float* __restrict__ wrec,
                               uint32_t* __restrict__ gtail, int n) {
    __shared__ uint32_t hist[NB];
    __shared__ uint32_t cur[NB];

    int chunk = (n + gridDim.x - 1) / gridDim.x;
    int start = blockIdx.x * chunk;
    int end = start + chunk; if (end > n) end = n;

    for (uint32_t k = threadIdx.x; k < NB; k += blockDim.x) hist[k] = 0;
    __syncthreads();

    // pass 1: per-block bucket histogram (LDS)
    for (int i = start + threadIdx.x; i < end; i += blockDim.x) {
        uint32_t ckey, t0;
        make_keys(tok, i, ckey, t0);
        uint32_t b = (hash32(ckey) >> 20) & BMASK;
        atomicAdd(&hist[b], 1u);
    }
    __syncthreads();

    // reserve contiguous runs per bucket: ONE global atomic per (block,bucket)
    for (uint32_t k = threadIdx.x; k < NB; k += blockDim.x) {
        uint32_t h = hist[k];
        cur[k] = h ? atomicAdd(&gtail[k], h) : 0u;
    }
    __syncthreads();

    // pass 2: place records + weights
    for (int i = start + threadIdx.x; i < end; i += blockDim.x) {
        uint32_t ckey, t0;
        make_keys(tok, i, ckey, t0);
        uint32_t b = (hash32(ckey) >> 20) & BMASK;
        uint64_t pkey = (((uint64_t)ckey) << 10) | (uint64_t)t0;   // 40 bits
        uint32_t j = atomicAdd(&cur[b], 1u);
        if (j < CAPB) {
            size_t slot = (size_t)b * CAPB + j;
            rec[slot] = (pkey << 22) | (uint64_t)(uint32_t)i;
            wrec[slot] = w[i];
        }
    }
}

// One block per bucket: count ckeys & pkeys in LDS, emit out[pos] = pc/(cc+1).
__global__ void __launch_bounds__(256) count_emit_kernel(
        const unsigned long long* __restrict__ rec,
        const float* __restrict__ wrec,
        const uint32_t* __restrict__ gtail,
        float* __restrict__ out) {
    __shared__ uint32_t ckk[LCAP];  __shared__ float ckc[LCAP];
    __shared__ uint32_t pkk[LCAP];  __shared__ float pkc[LCAP];

    uint32_t b = blockIdx.x;
    uint32_t m = gtail[b]; if (m > CAPB) m = CAPB;

    for (uint32_t k = threadIdx.x; k < LCAP; k += 256u) {
        ckk[k] = EMPTY; ckc[k] = 0.0f;
        pkk[k] = EMPTY; pkc[k] = 0.0f;
    }

    // Phase A: front-load all global reads (overlap with LDS init + barrier)
    unsigned long long ee[MAXIT];
    float wv[MAXIT];
    #pragma unroll
    for (uint32_t it = 0; it < MAXIT; ++it) {
        uint32_t r = threadIdx.x + it * 256u;
        if (r < m) {
            ee[it] = rec[(size_t)b * CAPB + r];
            wv[it] = wrec[(size_t)b * CAPB + r];
        }
    }
    __syncthreads();

    // Phase B: LDS insert-or-find + accumulate
    uint32_t ss[MAXIT], uu[MAXIT], pp[MAXIT];
    #pragma unroll
    for (uint32_t it = 0; it < MAXIT; ++it) {
        uint32_t r = threadIdx.x + it * 256u;
        ss[it] = EMPTY;
        if (r < m) {
            unsigned long long e = ee[it];
            uint32_t pos = (uint32_t)e & 0x3FFFFFu;
            uint64_t pkey = e >> 22;
            uint32_t ckey = (uint32_t)(pkey >> 10);
            uint32_t t0 = (uint32_t)pkey & 1023u;
            float wi = wv[it];

            // insert-or-find ckey (probe uses low hash bits; bucket used 20..31)
            uint32_t h = hash32(ckey) & LMASK;
            uint32_t s;
            while (true) {
                uint32_t prev = atomicCAS(&ckk[h], EMPTY, ckey);
                if (prev == EMPTY || prev == ckey) { s = h; break; }
                h = (h + 1u) & LMASK;
            }
            atomicAdd(&ckc[s], wi);

            // pair key within bucket: (ckey slot << 10) | t0  (21 bits)
            uint32_t pk2 = (s << 10) | t0;
            uint32_t h2 = hash32(pk2) & LMASK;
            uint32_t u;
            while (true) {
                uint32_t prev = atomicCAS(&pkk[h2], EMPTY, pk2);
                if (prev == EMPTY || prev == pk2) { u = h2; break; }
                h2 = (h2 + 1u) & LMASK;
            }
            atomicAdd(&pkc[u], wi);

            ss[it] = s; uu[it] = u; pp[it] = pos;
        }
    }
    __syncthreads();

    #pragma unroll
    for (uint32_t it = 0; it < MAXIT; ++it) {
        if (ss[it] != EMPTY) {
            float cc = ckc[ss[it]];
            float pc = pkc[uu[it]];
            out[pp[it]] = pc / (cc + 1.0f);
        }
    }
}

extern "C" void kernel_launch(void* const* d_in, const int* in_sizes, int n_in,
                              void* d_out, int out_size, void* d_ws, size_t ws_size,
                              hipStream_t stream) {
    const int* tok = (const int*)d_in[0];
    const float* w = (const float*)d_in[1];
    float* out = (float*)d_out;
    const int n = in_sizes[0];

    // ws layout: [0, 50.3MB) rec u64[NB*CAPB]; [50.3, 75.5MB) wrec f32; then gtail u32[NB]
    char* ws = (char*)d_ws;
    size_t nrec = (size_t)NB * CAPB;
    unsigned long long* rec = (unsigned long long*)ws;
    float* wrec = (float*)(ws + nrec * 8u);
    uint32_t* gtail = (uint32_t*)(ws + nrec * 12u);

    hipMemsetAsync(gtail, 0, NB * sizeof(uint32_t), stream);

    scatter_kernel<<<256, 256, 0, stream>>>(tok, w, rec, wrec, gtail, n);
    count_emit_kernel<<<NB, 256, 0, stream>>>(rec, wrec, gtail, out);
}

// Round 5
// 201.904 us; speedup vs baseline: 1.1446x; 1.1446x over previous
//
#include <hip/hip_runtime.h>
#include <stdint.h>

#define NB1   64u            // coarse buckets (hash bits 26..31)
#define CAP1  69632u         // per-coarse capacity (mean 65536, +16 sigma)
#define NB2   4096u          // fine buckets (hash bits 20..31)
#define CAPB  1536u          // per-fine capacity (mean 1024, +16 sigma)
#define LCAP  2048u          // LDS hash-table capacity (per table)
#define LMASK (LCAP - 1u)
#define EMPTY 0xFFFFFFFFu
#define MAXIT (CAPB / 256u)  // 6 records per thread max in count kernel

__device__ __forceinline__ uint32_t hash32(uint32_t x) {
    x *= 2654435761u;
    x ^= x >> 16;
    x *= 0x85ebca6bu;
    x ^= x >> 13;
    return x;
}

__device__ __forceinline__ void make_keys(const int* __restrict__ tok, int i,
                                          uint32_t& ckey, uint32_t& t0) {
    t0 = (uint32_t)tok[i];
    uint32_t t1 = (i >= 1) ? (uint32_t)tok[i - 1] : 0u;
    uint32_t t2 = (i >= 2) ? (uint32_t)tok[i - 2] : 0u;
    uint32_t t3 = (i >= 3) ? (uint32_t)tok[i - 3] : 0u;
    ckey = (t3 << 20) | (t2 << 10) | t1;   // 30-bit context key
}

// Record: u64 = (pkey40 << 22) | pos22 ; ckey = rec >> 32. Weight in wrec[].

// Pass 1: partition into 64 coarse buckets. Long runs (~64 rec) => ~1x write amp.
__global__ void scatter1_kernel(const int* __restrict__ tok,
                                const float* __restrict__ w,
                                unsigned long long* __restrict__ rec1,
                                float* __restrict__ wrec1,
                                uint32_t* __restrict__ gt1, int n) {
    __shared__ uint32_t hist[NB1];
    __shared__ uint32_t cur[NB1];

    int chunk = (n + gridDim.x - 1) / gridDim.x;
    int start = blockIdx.x * chunk;
    int end = start + chunk; if (end > n) end = n;

    if (threadIdx.x < NB1) hist[threadIdx.x] = 0;
    __syncthreads();

    for (int i = start + threadIdx.x; i < end; i += blockDim.x) {
        uint32_t ckey, t0;
        make_keys(tok, i, ckey, t0);
        atomicAdd(&hist[hash32(ckey) >> 26], 1u);
    }
    __syncthreads();

    if (threadIdx.x < NB1) {
        uint32_t h = hist[threadIdx.x];
        cur[threadIdx.x] = h ? atomicAdd(&gt1[threadIdx.x], h) : 0u;
    }
    __syncthreads();

    for (int i = start + threadIdx.x; i < end; i += blockDim.x) {
        uint32_t ckey, t0;
        make_keys(tok, i, ckey, t0);
        uint32_t c = hash32(ckey) >> 26;
        uint64_t pkey = (((uint64_t)ckey) << 10) | (uint64_t)t0;
        uint32_t j = atomicAdd(&cur[c], 1u);
        if (j < CAP1) {
            size_t slot = (size_t)c * CAP1 + j;
            rec1[slot] = (pkey << 22) | (uint64_t)(uint32_t)i;
            wrec1[slot] = w[i];
        }
    }
}

// Pass 2: refine each coarse bucket into 64 fine buckets (16 blocks/coarse).
__global__ void scatter2_kernel(const unsigned long long* __restrict__ rec1,
                                const float* __restrict__ wrec1,
                                const uint32_t* __restrict__ gt1,
                                unsigned long long* __restrict__ rec2,
                                float* __restrict__ wrec2,
                                uint32_t* __restrict__ gt2) {
    __shared__ uint32_t hist[64];
    __shared__ uint32_t cur[64];

    uint32_t c = blockIdx.x >> 4;        // coarse bucket
    uint32_t sl = blockIdx.x & 15u;      // slice within coarse bucket
    uint32_t m = gt1[c]; if (m > CAP1) m = CAP1;
    uint32_t per = (m + 15u) >> 4;
    uint32_t lo = sl * per;
    uint32_t hi = lo + per; if (hi > m) hi = m;

    if (threadIdx.x < 64u) hist[threadIdx.x] = 0;
    __syncthreads();

    for (uint32_t r = lo + threadIdx.x; r < hi; r += blockDim.x) {
        uint32_t ckey = (uint32_t)(rec1[(size_t)c * CAP1 + r] >> 32);
        atomicAdd(&hist[(hash32(ckey) >> 20) & 63u], 1u);
    }
    __syncthreads();

    if (threadIdx.x < 64u) {
        uint32_t h = hist[threadIdx.x];
        cur[threadIdx.x] = h ? atomicAdd(&gt2[c * 64u + threadIdx.x], h) : 0u;
    }
    __syncthreads();

    for (uint32_t r = lo + threadIdx.x; r < hi; r += blockDim.x) {
        size_t src = (size_t)c * CAP1 + r;
        unsigned long long e = rec1[src];
        uint32_t f = (hash32((uint32_t)(e >> 32)) >> 20) & 63u;
        uint32_t j = atomicAdd(&cur[f], 1u);
        if (j < CAPB) {
            size_t dst = (size_t)(c * 64u + f) * CAPB + j;
            rec2[dst] = e;
            wrec2[dst] = wrec1[src];
        }
    }
}

// One block per fine bucket: count ckeys & pkeys in LDS, emit out[pos]=pc/(cc+1).
__global__ void __launch_bounds__(256) count_emit_kernel(
        const unsigned long long* __restrict__ rec,
        const float* __restrict__ wrec,
        const uint32_t* __restrict__ gtail,
        float* __restrict__ out) {
    __shared__ uint32_t ckk[LCAP];  __shared__ float ckc[LCAP];
    __shared__ uint32_t pkk[LCAP];  __shared__ float pkc[LCAP];

    uint32_t b = blockIdx.x;
    uint32_t m = gtail[b]; if (m > CAPB) m = CAPB;

    for (uint32_t k = threadIdx.x; k < LCAP; k += 256u) {
        ckk[k] = EMPTY; ckc[k] = 0.0f;
        pkk[k] = EMPTY; pkc[k] = 0.0f;
    }

    unsigned long long ee[MAXIT];
    float wv[MAXIT];
    #pragma unroll
    for (uint32_t it = 0; it < MAXIT; ++it) {
        uint32_t r = threadIdx.x + it * 256u;
        if (r < m) {
            ee[it] = rec[(size_t)b * CAPB + r];
            wv[it] = wrec[(size_t)b * CAPB + r];
        }
    }
    __syncthreads();

    uint32_t ss[MAXIT], uu[MAXIT], pp[MAXIT];
    #pragma unroll
    for (uint32_t it = 0; it < MAXIT; ++it) {
        uint32_t r = threadIdx.x + it * 256u;
        ss[it] = EMPTY;
        if (r < m) {
            unsigned long long e = ee[it];
            uint32_t pos = (uint32_t)e & 0x3FFFFFu;
            uint64_t pkey = e >> 22;
            uint32_t ckey = (uint32_t)(pkey >> 10);
            uint32_t t0 = (uint32_t)pkey & 1023u;
            float wi = wv[it];

            uint32_t h = hash32(ckey) & LMASK;   // bits 0..10, indep of 20..31
            uint32_t s;
            while (true) {
                uint32_t prev = atomicCAS(&ckk[h], EMPTY, ckey);
                if (prev == EMPTY || prev == ckey) { s = h; break; }
                h = (h + 1u) & LMASK;
            }
            atomicAdd(&ckc[s], wi);

            uint32_t pk2 = (s << 10) | t0;       // 21-bit in-bucket pair key
            uint32_t h2 = hash32(pk2) & LMASK;
            uint32_t u;
            while (true) {
                uint32_t prev = atomicCAS(&pkk[h2], EMPTY, pk2);
                if (prev == EMPTY || prev == pk2) { u = h2; break; }
                h2 = (h2 + 1u) & LMASK;
            }
            atomicAdd(&pkc[u], wi);

            ss[it] = s; uu[it] = u; pp[it] = pos;
        }
    }
    __syncthreads();

    #pragma unroll
    for (uint32_t it = 0; it < MAXIT; ++it) {
        if (ss[it] != EMPTY) {
            out[pp[it]] = pkc[uu[it]] / (ckc[ss[it]] + 1.0f);
        }
    }
}

extern "C" void kernel_launch(void* const* d_in, const int* in_sizes, int n_in,
                              void* d_out, int out_size, void* d_ws, size_t ws_size,
                              hipStream_t stream) {
    const int* tok = (const int*)d_in[0];
    const float* w = (const float*)d_in[1];
    float* out = (float*)d_out;
    const int n = in_sizes[0];

    char* ws = (char*)d_ws;
    size_t n1 = (size_t)NB1 * CAP1;          // 4,456,448 coarse slots
    size_t n2 = (size_t)NB2 * CAPB;          // 6,291,456 fine slots
    unsigned long long* rec1 = (unsigned long long*)ws;             // 35.7 MB
    float* wrec1 = (float*)(ws + n1 * 8);                           // 17.8 MB
    unsigned long long* rec2 = (unsigned long long*)(ws + n1 * 12); // 50.3 MB
    float* wrec2 = (float*)(ws + n1 * 12 + n2 * 8);                 // 25.2 MB
    uint32_t* gt1 = (uint32_t*)(ws + n1 * 12 + n2 * 12);            // 64 u32
    uint32_t* gt2 = gt1 + NB1;                                      // 4096 u32

    hipMemsetAsync(gt1, 0, (NB1 + NB2) * sizeof(uint32_t), stream);

    scatter1_kernel<<<1024, 256, 0, stream>>>(tok, w, rec1, wrec1, gt1, n);
    scatter2_kernel<<<NB1 * 16, 256, 0, stream>>>(rec1, wrec1, gt1, rec2, wrec2, gt2);
    count_emit_kernel<<<NB2, 256, 0, stream>>>(rec2, wrec2, gt2, out);
}

// Round 6
// 163.900 us; speedup vs baseline: 1.4100x; 1.2319x over previous
//
#include <hip/hip_runtime.h>
#include <stdint.h>

#define NB1    64u           // coarse buckets (hash bits 26..31)
#define CAP1   69632u        // per-coarse capacity (mean 65536, +16 sigma)
#define NB2    4096u         // fine buckets (hash bits 20..31)
#define CAPB   1536u         // per-fine capacity (mean 1024, +16 sigma)
#define LCAP   2048u         // LDS hash-table capacity (per table)
#define LMASK  (LCAP - 1u)
#define EMPTY  0xFFFFFFFFu
#define MAXIT  (CAPB / 256u) // 6 records per thread in count kernel
#define CHUNK  4096u         // records per scatter block
#define STHR   512u          // scatter block size
#define NSLICE 17u           // slices per coarse bucket in scatter2

__device__ __forceinline__ uint32_t hash32(uint32_t x) {
    x *= 2654435761u;
    x ^= x >> 16;
    x *= 0x85ebca6bu;
    x ^= x >> 13;
    return x;
}

__device__ __forceinline__ void make_keys(const int* __restrict__ tok, int i,
                                          uint32_t& ckey, uint32_t& t0) {
    t0 = (uint32_t)tok[i];
    uint32_t t1 = (i >= 1) ? (uint32_t)tok[i - 1] : 0u;
    uint32_t t2 = (i >= 2) ? (uint32_t)tok[i - 2] : 0u;
    uint32_t t3 = (i >= 3) ? (uint32_t)tok[i - 3] : 0u;
    ckey = (t3 << 20) | (t2 << 10) | t1;   // 30-bit context key
}

// Record: u64 = (pkey40 << 22) | pos22 ; ckey = rec >> 32. Weight in wrec[].

// 64-entry exclusive scan + global reservation, done by wave 0 (lanes 0..63).
__device__ __forceinline__ void scan_reserve(uint32_t* hist, uint32_t* cur,
                                             uint32_t* scanb, uint32_t* gbase,
                                             uint32_t* gt, uint32_t gstride_id) {
    if (threadIdx.x < 64u) {
        uint32_t h = hist[threadIdx.x];
        uint32_t inc = h;
        #pragma unroll
        for (int d = 1; d < 64; d <<= 1) {
            uint32_t o = __shfl_up(inc, d, 64);
            if ((int)threadIdx.x >= d) inc += o;
        }
        uint32_t ex = inc - h;
        scanb[threadIdx.x] = ex;
        cur[threadIdx.x] = ex;
        gbase[threadIdx.x] = h ? atomicAdd(&gt[gstride_id + threadIdx.x], h) : 0u;
    }
}

// Pass 1: partition into 64 coarse buckets with LDS-sorted coalesced flush.
__global__ void __launch_bounds__(STHR) scatter1_kernel(
        const int* __restrict__ tok, const float* __restrict__ w,
        unsigned long long* __restrict__ rec1, float* __restrict__ wrec1,
        uint32_t* __restrict__ gt1, int n) {
    __shared__ uint32_t hist[NB1], cur[NB1], scanb[NB1], gbase[NB1];
    __shared__ unsigned long long srec[CHUNK];
    __shared__ float sw[CHUNK];

    int start = blockIdx.x * (int)CHUNK;
    int end = start + (int)CHUNK; if (end > n) end = n;
    int cnt = end - start;

    if (threadIdx.x < NB1) hist[threadIdx.x] = 0;
    __syncthreads();

    for (int i = start + threadIdx.x; i < end; i += STHR) {
        uint32_t ckey, t0;
        make_keys(tok, i, ckey, t0);
        atomicAdd(&hist[hash32(ckey) >> 26], 1u);
    }
    __syncthreads();

    scan_reserve(hist, cur, scanb, gbase, gt1, 0u);
    __syncthreads();

    // rank + stage in bucket-sorted order
    for (int i = start + threadIdx.x; i < end; i += STHR) {
        uint32_t ckey, t0;
        make_keys(tok, i, ckey, t0);
        uint32_t b = hash32(ckey) >> 26;
        uint64_t pkey = (((uint64_t)ckey) << 10) | (uint64_t)t0;
        uint32_t r = atomicAdd(&cur[b], 1u);
        srec[r] = (pkey << 22) | (uint64_t)(uint32_t)i;
        sw[r] = w[i];
    }
    __syncthreads();

    // coalesced flush: consecutive threads -> consecutive addresses per run
    for (uint32_t j = threadIdx.x; j < (uint32_t)cnt; j += STHR) {
        unsigned long long e = srec[j];
        uint32_t b = hash32((uint32_t)(e >> 32)) >> 26;
        uint32_t loc = gbase[b] + (j - scanb[b]);
        if (loc < CAP1) {
            size_t dst = (size_t)b * CAP1 + loc;
            rec1[dst] = e;
            wrec1[dst] = sw[j];
        }
    }
}

// Pass 2: refine each coarse bucket into 64 fine buckets, same staging trick.
__global__ void __launch_bounds__(STHR) scatter2_kernel(
        const unsigned long long* __restrict__ rec1,
        const float* __restrict__ wrec1,
        const uint32_t* __restrict__ gt1,
        unsigned long long* __restrict__ rec2, float* __restrict__ wrec2,
        uint32_t* __restrict__ gt2) {
    __shared__ uint32_t hist[64], cur[64], scanb[64], gbase[64];
    __shared__ unsigned long long srec[CHUNK];
    __shared__ float sw[CHUNK];

    uint32_t c = blockIdx.x / NSLICE;
    uint32_t sl = blockIdx.x % NSLICE;
    uint32_t m = gt1[c]; if (m > CAP1) m = CAP1;
    uint32_t lo = sl * CHUNK;
    if (lo >= m) return;
    uint32_t hi = lo + CHUNK; if (hi > m) hi = m;
    uint32_t cnt = hi - lo;
    size_t srcbase = (size_t)c * CAP1;

    if (threadIdx.x < 64u) hist[threadIdx.x] = 0;
    __syncthreads();

    for (uint32_t r = lo + threadIdx.x; r < hi; r += STHR) {
        uint32_t ckey = (uint32_t)(rec1[srcbase + r] >> 32);
        atomicAdd(&hist[(hash32(ckey) >> 20) & 63u], 1u);
    }
    __syncthreads();

    scan_reserve(hist, cur, scanb, gbase, gt2, c * 64u);
    __syncthreads();

    for (uint32_t r = lo + threadIdx.x; r < hi; r += STHR) {
        unsigned long long e = rec1[srcbase + r];
        uint32_t f = (hash32((uint32_t)(e >> 32)) >> 20) & 63u;
        uint32_t rk = atomicAdd(&cur[f], 1u);
        srec[rk] = e;
        sw[rk] = wrec1[srcbase + r];
    }
    __syncthreads();

    for (uint32_t j = threadIdx.x; j < cnt; j += STHR) {
        unsigned long long e = srec[j];
        uint32_t f = (hash32((uint32_t)(e >> 32)) >> 20) & 63u;
        uint32_t loc = gbase[f] + (j - scanb[f]);
        if (loc < CAPB) {
            size_t dst = (size_t)(c * 64u + f) * CAPB + loc;
            rec2[dst] = e;
            wrec2[dst] = sw[j];
        }
    }
}

// One block per fine bucket: count ckeys & pkeys in LDS, emit out[pos]=pc/(cc+1).
__global__ void __launch_bounds__(256) count_emit_kernel(
        const unsigned long long* __restrict__ rec,
        const float* __restrict__ wrec,
        const uint32_t* __restrict__ gtail,
        float* __restrict__ out) {
    __shared__ uint32_t ckk[LCAP];  __shared__ float ckc[LCAP];
    __shared__ uint32_t pkk[LCAP];  __shared__ float pkc[LCAP];

    uint32_t b = blockIdx.x;
    uint32_t m = gtail[b]; if (m > CAPB) m = CAPB;

    for (uint32_t k = threadIdx.x; k < LCAP; k += 256u) {
        ckk[k] = EMPTY; ckc[k] = 0.0f;
        pkk[k] = EMPTY; pkc[k] = 0.0f;
    }

    unsigned long long ee[MAXIT];
    float wv[MAXIT];
    #pragma unroll
    for (uint32_t it = 0; it < MAXIT; ++it) {
        uint32_t r = threadIdx.x + it * 256u;
        if (r < m) {
            ee[it] = rec[(size_t)b * CAPB + r];
            wv[it] = wrec[(size_t)b * CAPB + r];
        }
    }
    __syncthreads();

    uint32_t ss[MAXIT], uu[MAXIT], pp[MAXIT];
    #pragma unroll
    for (uint32_t it = 0; it < MAXIT; ++it) {
        uint32_t r = threadIdx.x + it * 256u;
        ss[it] = EMPTY;
        if (r < m) {
            unsigned long long e = ee[it];
            uint32_t pos = (uint32_t)e & 0x3FFFFFu;
            uint64_t pkey = e >> 22;
            uint32_t ckey = (uint32_t)(pkey >> 10);
            uint32_t t0 = (uint32_t)pkey & 1023u;
            float wi = wv[it];

            uint32_t h = hash32(ckey) & LMASK;   // bits 0..10, indep of 20..31
            uint32_t s;
            while (true) {
                uint32_t prev = atomicCAS(&ckk[h], EMPTY, ckey);
                if (prev == EMPTY || prev == ckey) { s = h; break; }
                h = (h + 1u) & LMASK;
            }
            atomicAdd(&ckc[s], wi);

            uint32_t pk2 = (s << 10) | t0;       // 21-bit in-bucket pair key
            uint32_t h2 = hash32(pk2) & LMASK;
            uint32_t u;
            while (true) {
                uint32_t prev = atomicCAS(&pkk[h2], EMPTY, pk2);
                if (prev == EMPTY || prev == pk2) { u = h2; break; }
                h2 = (h2 + 1u) & LMASK;
            }
            atomicAdd(&pkc[u], wi);

            ss[it] = s; uu[it] = u; pp[it] = pos;
        }
    }
    __syncthreads();

    #pragma unroll
    for (uint32_t it = 0; it < MAXIT; ++it) {
        if (ss[it] != EMPTY) {
            out[pp[it]] = pkc[uu[it]] / (ckc[ss[it]] + 1.0f);
        }
    }
}

extern "C" void kernel_launch(void* const* d_in, const int* in_sizes, int n_in,
                              void* d_out, int out_size, void* d_ws, size_t ws_size,
                              hipStream_t stream) {
    const int* tok = (const int*)d_in[0];
    const float* w = (const float*)d_in[1];
    float* out = (float*)d_out;
    const int n = in_sizes[0];

    char* ws = (char*)d_ws;
    size_t n1 = (size_t)NB1 * CAP1;          // 4,456,448 coarse slots
    size_t n2 = (size_t)NB2 * CAPB;          // 6,291,456 fine slots
    unsigned long long* rec1 = (unsigned long long*)ws;             // 35.7 MB
    float* wrec1 = (float*)(ws + n1 * 8);                           // 17.8 MB
    unsigned long long* rec2 = (unsigned long long*)(ws + n1 * 12); // 50.3 MB
    float* wrec2 = (float*)(ws + n1 * 12 + n2 * 8);                 // 25.2 MB
    uint32_t* gt1 = (uint32_t*)(ws + n1 * 12 + n2 * 12);            // 64 u32
    uint32_t* gt2 = gt1 + NB1;                                      // 4096 u32

    hipMemsetAsync(gt1, 0, (NB1 + NB2) * sizeof(uint32_t), stream);

    int g1 = (n + (int)CHUNK - 1) / (int)CHUNK;       // 1024 for n=2^22
    scatter1_kernel<<<g1, STHR, 0, stream>>>(tok, w, rec1, wrec1, gt1, n);
    scatter2_kernel<<<NB1 * NSLICE, STHR, 0, stream>>>(rec1, wrec1, gt1, rec2, wrec2, gt2);
    count_emit_kernel<<<NB2, 256, 0, stream>>>(rec2, wrec2, gt2, out);
}